// Round 1
// baseline (11642.145 us; speedup 1.0000x reference)
//
#include <hip/hip_runtime.h>
#include <cstddef>

#define B 2048
#define T 128
#define S 16
#define NL 128
#define IN 32
#define OUT 8
#define DT 0.01f
#define FP_ITERS 30

#define BB 8            // batch rows per block
#define NBLK (B / BB)   // 256 blocks -> 1 per CU
#define NTHR 256
#define A2S 132         // padded stride for Dvw (transposed), bank-spread + 16B aligned
#define WNS 132         // padded stride for w

struct alignas(16) SmemA {
    float A2[NL][A2S];        // A2[c][k] = Dvw_T[k][c]  (column-major of Dvw_T)
    float wN[BB][WNS];        // w, row-major, k-contiguous
    float cblk[BB][32][4];    // const, blocked: col c = c' + 32*j  -> cblk[r][c'][j]
    float part[4][BB][32][4]; // k-split partials per wave
    float Cv[S][NL];
    float Dvy[IN][NL];
    float Bw[NL][S];
    float By[IN][S];
    float Amat[S][S];
    float Cu[S][OUT];
    float Duw[NL][OUT];
    float Duy[IN][OUT];
    float xs[BB][S];
    float ys[BB][IN];
    float xnew[BB][S];
    float ls[OUT];
};

__device__ __forceinline__ float fast_tanh(float x) {
    x = fminf(fmaxf(x, -15.f), 15.f);
    float e = __expf(2.f * x);
    return 1.f - 2.f * __builtin_amdgcn_rcpf(e + 1.f);
}

__global__ void __launch_bounds__(NTHR, 1)
rinn_kernel(const float* __restrict__ obs, const float* __restrict__ x0,
            const float* __restrict__ A_T, const float* __restrict__ Bw_T,
            const float* __restrict__ By_T, const float* __restrict__ Cv_T,
            const float* __restrict__ Dvw_T, const float* __restrict__ Dvy_T,
            const float* __restrict__ Cu_T, const float* __restrict__ Duw_T,
            const float* __restrict__ Duy_T, const float* __restrict__ log_stds,
            float* __restrict__ out) {
    extern __shared__ char smem_raw[];
    SmemA& sm = *reinterpret_cast<SmemA*>(smem_raw);
    const int tid = threadIdx.x;
    const int b0 = blockIdx.x * BB;

    // ---- stage weights into LDS ----
    for (int i = tid; i < NL * NL; i += NTHR) sm.A2[i & 127][i >> 7] = Dvw_T[i];
    for (int i = tid; i < S * NL; i += NTHR) ((float*)sm.Cv)[i] = Cv_T[i];
    for (int i = tid; i < IN * NL; i += NTHR) ((float*)sm.Dvy)[i] = Dvy_T[i];
    for (int i = tid; i < NL * S; i += NTHR) ((float*)sm.Bw)[i] = Bw_T[i];
    for (int i = tid; i < IN * S; i += NTHR) ((float*)sm.By)[i] = By_T[i];
    for (int i = tid; i < S * S; i += NTHR) ((float*)sm.Amat)[i] = A_T[i];
    for (int i = tid; i < S * OUT; i += NTHR) ((float*)sm.Cu)[i] = Cu_T[i];
    for (int i = tid; i < NL * OUT; i += NTHR) ((float*)sm.Duw)[i] = Duw_T[i];
    for (int i = tid; i < IN * OUT; i += NTHR) ((float*)sm.Duy)[i] = Duy_T[i];
    if (tid < OUT) sm.ls[tid] = log_stds[tid];
    if (tid < BB * S) {
        int r = tid >> 4, sc = tid & 15;
        sm.xs[r][sc] = x0[(b0 + r) * S + sc];
    }
    __syncthreads();

    const int wv = tid >> 6;          // wave id 0..3 (k-range owner)
    const int lane = tid & 63;
    const int rg = lane >> 5;         // row group 0..1 (rows rg*4..rg*4+3)
    const int cg = lane & 31;         // col group (cols cg + 32*j)
    const int kbase = wv * 32;

    for (int t = 0; t < T; ++t) {
        // load y tile
        {
            int r = tid >> 5, i2 = tid & 31;
            sm.ys[r][i2] = obs[((size_t)(b0 + r) * T + t) * IN + i2];
        }
        __syncthreads();

        // const = x@Cv_T + y@Dvy_T  (blocked layout) and w1 = tanh(const)
        {
            int rr = tid >> 5, cc = tid & 31;
            float z[4];
#pragma unroll
            for (int j = 0; j < 4; ++j) {
                int c = cc + 32 * j;
                float a = 0.f;
#pragma unroll
                for (int k = 0; k < S; ++k) a = fmaf(sm.xs[rr][k], sm.Cv[k][c], a);
#pragma unroll
                for (int k = 0; k < IN; ++k) a = fmaf(sm.ys[rr][k], sm.Dvy[k][c], a);
                z[j] = a;
            }
            float4 cb; cb.x = z[0]; cb.y = z[1]; cb.z = z[2]; cb.w = z[3];
            *(float4*)&sm.cblk[rr][cc][0] = cb;
            sm.wN[rr][cc]      = fast_tanh(z[0]);
            sm.wN[rr][cc + 32] = fast_tanh(z[1]);
            sm.wN[rr][cc + 64] = fast_tanh(z[2]);
            sm.wN[rr][cc + 96] = fast_tanh(z[3]);
        }
        __syncthreads();

        // fixed-point iterations 2..30 (w <- tanh(const + w @ Dvw_T))
        for (int it = 1; it < FP_ITERS; ++it) {
            float acc[4][4];
#pragma unroll
            for (int i = 0; i < 4; ++i)
#pragma unroll
                for (int j = 0; j < 4; ++j) acc[i][j] = 0.f;

#pragma unroll
            for (int s = 0; s < 8; ++s) {
                const int kk = kbase + 4 * s;
                float4 wr[4], dv[4];
#pragma unroll
                for (int i = 0; i < 4; ++i)
                    wr[i] = *(const float4*)&sm.wN[rg * 4 + i][kk];
#pragma unroll
                for (int j = 0; j < 4; ++j)
                    dv[j] = *(const float4*)&sm.A2[cg + 32 * j][kk];
#pragma unroll
                for (int i = 0; i < 4; ++i)
#pragma unroll
                    for (int j = 0; j < 4; ++j) {
                        float a = acc[i][j];
                        a = fmaf(wr[i].x, dv[j].x, a);
                        a = fmaf(wr[i].y, dv[j].y, a);
                        a = fmaf(wr[i].z, dv[j].z, a);
                        a = fmaf(wr[i].w, dv[j].w, a);
                        acc[i][j] = a;
                    }
            }
#pragma unroll
            for (int i = 0; i < 4; ++i) {
                float4 p; p.x = acc[i][0]; p.y = acc[i][1]; p.z = acc[i][2]; p.w = acc[i][3];
                *(float4*)&sm.part[wv][rg * 4 + i][cg][0] = p;
            }
            __syncthreads();
            {
                int rr = tid >> 5, cc = tid & 31;
                float4 p0 = *(const float4*)&sm.part[0][rr][cc][0];
                float4 p1 = *(const float4*)&sm.part[1][rr][cc][0];
                float4 p2 = *(const float4*)&sm.part[2][rr][cc][0];
                float4 p3 = *(const float4*)&sm.part[3][rr][cc][0];
                float4 cb = *(const float4*)&sm.cblk[rr][cc][0];
                sm.wN[rr][cc]      = fast_tanh(cb.x + ((p0.x + p1.x) + (p2.x + p3.x)));
                sm.wN[rr][cc + 32] = fast_tanh(cb.y + ((p0.y + p1.y) + (p2.y + p3.y)));
                sm.wN[rr][cc + 64] = fast_tanh(cb.z + ((p0.z + p1.z) + (p2.z + p3.z)));
                sm.wN[rr][cc + 96] = fast_tanh(cb.w + ((p0.w + p1.w) + (p2.w + p3.w)));
            }
            __syncthreads();
        }

        // u (wave 0) and x_next (waves 1-2)
        if (tid < 64) {
            int r = tid >> 3, oc = tid & 7;
            float a = 0.f;
#pragma unroll
            for (int k = 0; k < S; ++k) a = fmaf(sm.xs[r][k], sm.Cu[k][oc], a);
            for (int k = 0; k < NL; ++k) a = fmaf(sm.wN[r][k], sm.Duw[k][oc], a);
#pragma unroll
            for (int k = 0; k < IN; ++k) a = fmaf(sm.ys[r][k], sm.Duy[k][oc], a);
            size_t o = ((size_t)(b0 + r) * T + t) * (2 * OUT + 1);
            out[o + oc] = a;
            out[o + OUT + oc] = sm.ls[oc];
        } else if (tid < 192) {
            int q = tid - 64;
            int r = q >> 4, sc = q & 15;
            float a = 0.f;
#pragma unroll
            for (int k = 0; k < S; ++k) a = fmaf(sm.xs[r][k], sm.Amat[k][sc], a);
            for (int k = 0; k < NL; ++k) a = fmaf(sm.wN[r][k], sm.Bw[k][sc], a);
#pragma unroll
            for (int k = 0; k < IN; ++k) a = fmaf(sm.ys[r][k], sm.By[k][sc], a);
            sm.xnew[r][sc] = fmaf(DT, a, sm.xs[r][sc]);
        }
        __syncthreads();
        if (tid < BB * S) {
            int r = tid >> 4, sc = tid & 15;
            sm.xs[r][sc] = sm.xnew[r][sc];
        }
        // commit of xs becomes visible at the barrier after next t's ys load;
        // all readers of xs finished before the barrier above.
    }
}

// ---------------- value branch ----------------
__global__ void __launch_bounds__(256)
value_kernel(const float* __restrict__ obs, const float* __restrict__ W0,
             const float* __restrict__ b0, const float* __restrict__ W1,
             const float* __restrict__ b1, const float* __restrict__ W2,
             const float* __restrict__ b2, float* __restrict__ out) {
    __shared__ float sW0[IN][64];
    __shared__ float sW1[64][64];
    __shared__ float sW2[64], sb0[64], sb1[64];
    __shared__ float sb2;
    const int tid = threadIdx.x;
    for (int i = tid; i < IN * 64; i += 256) ((float*)sW0)[i] = W0[i];
    for (int i = tid; i < 64 * 64; i += 256) ((float*)sW1)[i] = W1[i];
    if (tid < 64) { sW2[tid] = W2[tid]; sb0[tid] = b0[tid]; sb1[tid] = b1[tid]; }
    if (tid == 0) sb2 = b2[0];
    __syncthreads();

    const size_t s = (size_t)blockIdx.x * 256 + tid;  // sample = b*T + t
    float o[IN];
#pragma unroll
    for (int q = 0; q < IN / 4; ++q) {
        float4 v = ((const float4*)(obs + s * IN))[q];
        o[4 * q] = v.x; o[4 * q + 1] = v.y; o[4 * q + 2] = v.z; o[4 * q + 3] = v.w;
    }
    float h[64];
#pragma unroll
    for (int jg = 0; jg < 16; ++jg) {
        float4 a = *(const float4*)&sb0[4 * jg];
#pragma unroll
        for (int i = 0; i < IN; ++i) {
            float4 wrow = *(const float4*)&sW0[i][4 * jg];
            a.x = fmaf(o[i], wrow.x, a.x);
            a.y = fmaf(o[i], wrow.y, a.y);
            a.z = fmaf(o[i], wrow.z, a.z);
            a.w = fmaf(o[i], wrow.w, a.w);
        }
        h[4 * jg]     = fast_tanh(a.x);
        h[4 * jg + 1] = fast_tanh(a.y);
        h[4 * jg + 2] = fast_tanh(a.z);
        h[4 * jg + 3] = fast_tanh(a.w);
    }
    float value = sb2;
#pragma unroll
    for (int jg = 0; jg < 16; ++jg) {
        float4 a = *(const float4*)&sb1[4 * jg];
#pragma unroll
        for (int i = 0; i < 64; ++i) {
            float4 wrow = *(const float4*)&sW1[i][4 * jg];
            a.x = fmaf(h[i], wrow.x, a.x);
            a.y = fmaf(h[i], wrow.y, a.y);
            a.z = fmaf(h[i], wrow.z, a.z);
            a.w = fmaf(h[i], wrow.w, a.w);
        }
        float4 w2 = *(const float4*)&sW2[4 * jg];
        value = fmaf(fast_tanh(a.x), w2.x, value);
        value = fmaf(fast_tanh(a.y), w2.y, value);
        value = fmaf(fast_tanh(a.z), w2.z, value);
        value = fmaf(fast_tanh(a.w), w2.w, value);
    }
    out[s * (2 * OUT + 1) + 2 * OUT] = value;
}

extern "C" void kernel_launch(void* const* d_in, const int* in_sizes, int n_in,
                              void* d_out, int out_size, void* d_ws, size_t ws_size,
                              hipStream_t stream) {
    const float* obs      = (const float*)d_in[0];
    const float* x0       = (const float*)d_in[1];
    const float* A_T      = (const float*)d_in[2];
    const float* Bw_T     = (const float*)d_in[3];
    const float* By_T     = (const float*)d_in[4];
    const float* Cv_T     = (const float*)d_in[5];
    const float* Dvw_T    = (const float*)d_in[6];
    const float* Dvy_T    = (const float*)d_in[7];
    const float* Cu_T     = (const float*)d_in[8];
    const float* Duw_T    = (const float*)d_in[9];
    const float* Duy_T    = (const float*)d_in[10];
    const float* log_stds = (const float*)d_in[11];
    const float* W0       = (const float*)d_in[12];
    const float* b0       = (const float*)d_in[13];
    const float* W1       = (const float*)d_in[14];
    const float* b1       = (const float*)d_in[15];
    const float* W2       = (const float*)d_in[16];
    const float* b2       = (const float*)d_in[17];
    float* out = (float*)d_out;

    (void)hipFuncSetAttribute((const void*)rinn_kernel,
                              hipFuncAttributeMaxDynamicSharedMemorySize,
                              (int)sizeof(SmemA));
    rinn_kernel<<<NBLK, NTHR, sizeof(SmemA), stream>>>(
        obs, x0, A_T, Bw_T, By_T, Cv_T, Dvw_T, Dvy_T, Cu_T, Duw_T, Duy_T,
        log_stds, out);
    value_kernel<<<(B * T) / 256, 256, 0, stream>>>(obs, W0, b0, W1, b1, W2, b2,
                                                    out);
}

// Round 2
// 1395.830 us; speedup vs baseline: 8.3407x; 8.3407x over previous
//
#include <hip/hip_runtime.h>
#include <cstddef>

#define B 2048
#define T 128
#define S 16
#define NL 128
#define IN 32
#define OUT 8
#define DT 0.01f
#define FP_ITERS 30

#define NTHR 512
#define NBLK (B / 16)   // 128 blocks, 16 batch rows each

typedef unsigned int uint;
typedef unsigned short ushort;
typedef __bf16 bf16x8 __attribute__((ext_vector_type(8)));
typedef float f32x4 __attribute__((ext_vector_type(4)));

union ABu { bf16x8 v; ushort u[8]; };

__device__ __forceinline__ float fast_tanh(float x) {
    x = fminf(fmaxf(x, -15.f), 15.f);
    float e = __expf(2.f * x);
    return 1.f - 2.f * __builtin_amdgcn_rcpf(e + 1.f);
}

// fp32 -> bf16 bits, round-to-nearest-even (inputs are finite/bounded here)
__device__ __forceinline__ ushort f2bf(float f) {
    uint u = __float_as_uint(f);
    uint r = (u + 0x7fffu + ((u >> 16) & 1u)) >> 16;
    return (ushort)r;
}

// LDS chunk layout for a 16(batch m) x 128(k) bf16 matrix:
// chunk (cc = k>>3, m) is 8 consecutive k's of row m, stored at byte
// offset ((cc*16 + m)*16 + (k&7)*2.  A wave's B-fragment read for k-step s
// (quad q, lane m) is one 16B ds_read_b128 at ((s*4+q)*16 + m)*16.

__global__ void __launch_bounds__(NTHR, 1)
rinn_kernel(const float* __restrict__ obs, const float* __restrict__ x0,
            const float* __restrict__ A_T, const float* __restrict__ Bw_T,
            const float* __restrict__ By_T, const float* __restrict__ Cv_T,
            const float* __restrict__ Dvw_T, const float* __restrict__ Dvy_T,
            const float* __restrict__ Cu_T, const float* __restrict__ Duw_T,
            const float* __restrict__ Duy_T, const float* __restrict__ log_stds,
            float* __restrict__ out) {
    __shared__ __align__(16) char wbuf_raw[2][4096];  // w (16x128 bf16), dbuf
    __shared__ __align__(16) char xy_raw[2048];       // [x|y|0] (16x64 bf16)
    __shared__ float xs[16][16];
    __shared__ float ls[OUT];

    const int tid  = threadIdx.x;
    const int wave = tid >> 6;
    const int lane = tid & 63;
    const int q    = lane >> 4;   // quad 0..3
    const int l15  = lane & 15;
    const int b0   = blockIdx.x * 16;
    const int c0   = wave * 16;   // this wave's 16-column tile of the NL dim

    // ---- init: xs, ls, zero pad region of xy (k=48..63 -> chunk cols 6,7) ----
    if (tid < 256) { int m = tid >> 4, c = tid & 15; xs[m][c] = x0[(b0 + m) * S + c]; }
    if (tid < OUT) ls[tid] = log_stds[tid];
    if (tid < 128) ((uint*)(xy_raw + 1536))[tid] = 0u;

    // ---- preload MFMA A-operand fragments (all iteration-invariant) ----
    // Iteration matmul (transposed): Z^T = Dvw^T (A) * w^T (B).
    // A[c_local][k]: c = c0 + l15, k = 32s + 8q + j  ->  Dvw_T[k*128 + c]
    ABu Dfrag[4];
#pragma unroll
    for (int s = 0; s < 4; ++s)
#pragma unroll
        for (int j = 0; j < 8; ++j) {
            int k = 32 * s + 8 * q + j;
            Dfrag[s].u[j] = f2bf(Dvw_T[k * NL + c0 + l15]);
        }
    // const matmul: cst^T = [Cv;Dvy;0]^T (A) * [x|y|0]^T (B), K=64
    ABu CB[2];
#pragma unroll
    for (int s = 0; s < 2; ++s)
#pragma unroll
        for (int j = 0; j < 8; ++j) {
            int k = 32 * s + 8 * q + j;
            float v = 0.f;
            if (k < 16) v = Cv_T[k * NL + c0 + l15];
            else if (k < 48) v = Dvy_T[(k - 16) * NL + c0 + l15];
            CB[s].u[j] = f2bf(v);
        }
    // epilogue matmul: [u|xn]^T = W^T (A) * [x|y|0|w]^T (B), K=192, outs 0..23
    ABu EP[6];
    if (wave < 2) {
        int oc = wave * 16 + l15;  // 0..7 = u, 8..23 = xnext, >=24 pad
#pragma unroll
        for (int s = 0; s < 6; ++s)
#pragma unroll
            for (int j = 0; j < 8; ++j) {
                int k = 32 * s + 8 * q + j;
                float v = 0.f;
                if (oc < 24) {
                    if (k < 16)      v = (oc < 8) ? Cu_T[k * OUT + oc]  : A_T[k * S + (oc - 8)];
                    else if (k < 48) { int ky = k - 16;
                                       v = (oc < 8) ? Duy_T[ky * OUT + oc] : By_T[ky * S + (oc - 8)]; }
                    else if (k >= 64) { int kw = k - 64;
                                       v = (oc < 8) ? Duw_T[kw * OUT + oc] : Bw_T[kw * S + (oc - 8)]; }
                }
                EP[s].u[j] = f2bf(v);
            }
    }

    // per-lane LDS addresses
    const int rd_off = (q * 16 + l15) * 16;                       // + s*1024
    const int waddr  = (((c0 >> 3) + (q >> 1)) * 16 + l15) * 16 + (q & 1) * 8;

    __syncthreads();

    for (int t = 0; t < T; ++t) {
        // ---- stage [x|y] into xy (bf16 chunk layout) ----
        if (tid < 384) {
            int m = tid / 24, kp = tid % 24;
            int k = kp * 2;
            float v0, v1;
            if (k < 16) { v0 = xs[m][k]; v1 = xs[m][k + 1]; }
            else {
                const float* yp = obs + ((size_t)(b0 + m) * T + t) * IN + (k - 16);
                v0 = yp[0]; v1 = yp[1];
            }
            uint pk = (uint)f2bf(v0) | ((uint)f2bf(v1) << 16);
            *(uint*)(xy_raw + ((k >> 3) * 16 + m) * 16 + ((k & 7) >> 1) * 4) = pk;
        }
        __syncthreads();

        // ---- cst = ([x|y] @ [Cv;Dvy])^T tile, fp32, stays in registers ----
        f32x4 cst = {0.f, 0.f, 0.f, 0.f};
        {
            bf16x8 bx0 = *(const bf16x8*)(xy_raw + rd_off);
            bf16x8 bx1 = *(const bf16x8*)(xy_raw + rd_off + 1024);
            cst = __builtin_amdgcn_mfma_f32_16x16x32_bf16(CB[0].v, bx0, cst, 0, 0, 0);
            cst = __builtin_amdgcn_mfma_f32_16x16x32_bf16(CB[1].v, bx1, cst, 0, 0, 0);
        }

        // ---- iteration 1: w = tanh(cst) ----
        {
            float t0 = fast_tanh(cst.x), t1 = fast_tanh(cst.y);
            float t2 = fast_tanh(cst.z), t3 = fast_tanh(cst.w);
            uint2 pk;
            pk.x = (uint)f2bf(t0) | ((uint)f2bf(t1) << 16);
            pk.y = (uint)f2bf(t2) | ((uint)f2bf(t3) << 16);
            *(uint2*)(wbuf_raw[0] + waddr) = pk;
        }
        __syncthreads();

        // ---- iterations 2..30 ----
        int pb = 0;
        for (int it = 1; it < FP_ITERS; ++it) {
            const char* rb = wbuf_raw[pb];
            bf16x8 a0 = *(const bf16x8*)(rb + rd_off);
            bf16x8 a1 = *(const bf16x8*)(rb + rd_off + 1024);
            bf16x8 a2 = *(const bf16x8*)(rb + rd_off + 2048);
            bf16x8 a3 = *(const bf16x8*)(rb + rd_off + 3072);
            f32x4 acc = cst;
            acc = __builtin_amdgcn_mfma_f32_16x16x32_bf16(Dfrag[0].v, a0, acc, 0, 0, 0);
            acc = __builtin_amdgcn_mfma_f32_16x16x32_bf16(Dfrag[1].v, a1, acc, 0, 0, 0);
            acc = __builtin_amdgcn_mfma_f32_16x16x32_bf16(Dfrag[2].v, a2, acc, 0, 0, 0);
            acc = __builtin_amdgcn_mfma_f32_16x16x32_bf16(Dfrag[3].v, a3, acc, 0, 0, 0);
            float t0 = fast_tanh(acc.x), t1 = fast_tanh(acc.y);
            float t2 = fast_tanh(acc.z), t3 = fast_tanh(acc.w);
            pb ^= 1;
            uint2 pk;
            pk.x = (uint)f2bf(t0) | ((uint)f2bf(t1) << 16);
            pk.y = (uint)f2bf(t2) | ((uint)f2bf(t3) << 16);
            *(uint2*)(wbuf_raw[pb] + waddr) = pk;
            __syncthreads();
        }
        // final w is in wbuf_raw[1]  (29 & 1)

        // ---- epilogue: u (global), x_next (xs update), log_stds ----
        if (wave < 2) {
            f32x4 ea = {0.f, 0.f, 0.f, 0.f};
            bf16x8 bx0 = *(const bf16x8*)(xy_raw + rd_off);
            bf16x8 bx1 = *(const bf16x8*)(xy_raw + rd_off + 1024);
            ea = __builtin_amdgcn_mfma_f32_16x16x32_bf16(EP[0].v, bx0, ea, 0, 0, 0);
            ea = __builtin_amdgcn_mfma_f32_16x16x32_bf16(EP[1].v, bx1, ea, 0, 0, 0);
            const char* rb = wbuf_raw[1];
#pragma unroll
            for (int s = 0; s < 4; ++s) {
                bf16x8 aw = *(const bf16x8*)(rb + rd_off + s * 1024);
                ea = __builtin_amdgcn_mfma_f32_16x16x32_bf16(EP[2 + s].v, aw, ea, 0, 0, 0);
            }
            const int m = l15;
            const size_t o = ((size_t)(b0 + m) * T + t) * (2 * OUT + 1);
            float e[4] = {ea.x, ea.y, ea.z, ea.w};
            if (wave == 0) {
                if (q < 2) {           // rows 0..7: u
#pragma unroll
                    for (int i = 0; i < 4; ++i) out[o + 4 * q + i] = e[i];
                } else {               // rows 8..15: xnext cols 0..7
                    int cb = 4 * q - 8;
#pragma unroll
                    for (int i = 0; i < 4; ++i)
                        xs[m][cb + i] = fmaf(DT, e[i], xs[m][cb + i]);
                }
            } else {
                if (q < 2) {           // rows 16..23: xnext cols 8..15
                    int cb = 8 + 4 * q;
#pragma unroll
                    for (int i = 0; i < 4; ++i)
                        xs[m][cb + i] = fmaf(DT, e[i], xs[m][cb + i]);
                }                      // rows 24..31: padding, drop
            }
        } else if (wave == 2) {        // log_stds columns
            const int m = l15;
            const size_t o = ((size_t)(b0 + m) * T + t) * (2 * OUT + 1);
            out[o + OUT + 2 * q]     = ls[2 * q];
            out[o + OUT + 2 * q + 1] = ls[2 * q + 1];
        }
        __syncthreads();
    }
}

// ---------------- value branch (unchanged) ----------------
__global__ void __launch_bounds__(256)
value_kernel(const float* __restrict__ obs, const float* __restrict__ W0,
             const float* __restrict__ b0, const float* __restrict__ W1,
             const float* __restrict__ b1, const float* __restrict__ W2,
             const float* __restrict__ b2, float* __restrict__ out) {
    __shared__ float sW0[IN][64];
    __shared__ float sW1[64][64];
    __shared__ float sW2[64], sb0[64], sb1[64];
    __shared__ float sb2;
    const int tid = threadIdx.x;
    for (int i = tid; i < IN * 64; i += 256) ((float*)sW0)[i] = W0[i];
    for (int i = tid; i < 64 * 64; i += 256) ((float*)sW1)[i] = W1[i];
    if (tid < 64) { sW2[tid] = W2[tid]; sb0[tid] = b0[tid]; sb1[tid] = b1[tid]; }
    if (tid == 0) sb2 = b2[0];
    __syncthreads();

    const size_t s = (size_t)blockIdx.x * 256 + tid;
    float o[IN];
#pragma unroll
    for (int qq = 0; qq < IN / 4; ++qq) {
        float4 v = ((const float4*)(obs + s * IN))[qq];
        o[4 * qq] = v.x; o[4 * qq + 1] = v.y; o[4 * qq + 2] = v.z; o[4 * qq + 3] = v.w;
    }
    float h[64];
#pragma unroll
    for (int jg = 0; jg < 16; ++jg) {
        float4 a = *(const float4*)&sb0[4 * jg];
#pragma unroll
        for (int i = 0; i < IN; ++i) {
            float4 wrow = *(const float4*)&sW0[i][4 * jg];
            a.x = fmaf(o[i], wrow.x, a.x);
            a.y = fmaf(o[i], wrow.y, a.y);
            a.z = fmaf(o[i], wrow.z, a.z);
            a.w = fmaf(o[i], wrow.w, a.w);
        }
        h[4 * jg]     = fast_tanh(a.x);
        h[4 * jg + 1] = fast_tanh(a.y);
        h[4 * jg + 2] = fast_tanh(a.z);
        h[4 * jg + 3] = fast_tanh(a.w);
    }
    float value = sb2;
#pragma unroll
    for (int jg = 0; jg < 16; ++jg) {
        float4 a = *(const float4*)&sb1[4 * jg];
#pragma unroll
        for (int i = 0; i < 64; ++i) {
            float4 wrow = *(const float4*)&sW1[i][4 * jg];
            a.x = fmaf(h[i], wrow.x, a.x);
            a.y = fmaf(h[i], wrow.y, a.y);
            a.z = fmaf(h[i], wrow.z, a.z);
            a.w = fmaf(h[i], wrow.w, a.w);
        }
        float4 w2 = *(const float4*)&sW2[4 * jg];
        value = fmaf(fast_tanh(a.x), w2.x, value);
        value = fmaf(fast_tanh(a.y), w2.y, value);
        value = fmaf(fast_tanh(a.z), w2.z, value);
        value = fmaf(fast_tanh(a.w), w2.w, value);
    }
    out[s * (2 * OUT + 1) + 2 * OUT] = value;
}

extern "C" void kernel_launch(void* const* d_in, const int* in_sizes, int n_in,
                              void* d_out, int out_size, void* d_ws, size_t ws_size,
                              hipStream_t stream) {
    const float* obs      = (const float*)d_in[0];
    const float* x0       = (const float*)d_in[1];
    const float* A_T      = (const float*)d_in[2];
    const float* Bw_T     = (const float*)d_in[3];
    const float* By_T     = (const float*)d_in[4];
    const float* Cv_T     = (const float*)d_in[5];
    const float* Dvw_T    = (const float*)d_in[6];
    const float* Dvy_T    = (const float*)d_in[7];
    const float* Cu_T     = (const float*)d_in[8];
    const float* Duw_T    = (const float*)d_in[9];
    const float* Duy_T    = (const float*)d_in[10];
    const float* log_stds = (const float*)d_in[11];
    const float* W0       = (const float*)d_in[12];
    const float* b0       = (const float*)d_in[13];
    const float* W1       = (const float*)d_in[14];
    const float* b1       = (const float*)d_in[15];
    const float* W2       = (const float*)d_in[16];
    const float* b2       = (const float*)d_in[17];
    float* out = (float*)d_out;

    rinn_kernel<<<NBLK, NTHR, 0, stream>>>(
        obs, x0, A_T, Bw_T, By_T, Cv_T, Dvw_T, Dvy_T, Cu_T, Duw_T, Duy_T,
        log_stds, out);
    value_kernel<<<(B * T) / 256, 256, 0, stream>>>(obs, W0, b0, W1, b1, W2, b2,
                                                    out);
}

// Round 3
// 1318.157 us; speedup vs baseline: 8.8321x; 1.0589x over previous
//
#include <hip/hip_runtime.h>
#include <cstddef>

#define B 2048
#define T 128
#define S 16
#define NL 128
#define IN 32
#define OUT 8
#define DT 0.01f
#define FP_ITERS 30

#define RB 8            // batch rows per block (half-filled MFMA N dim)
#define NTHR 512
#define NBLK (B / RB)   // 256 blocks -> every CU busy

typedef unsigned int uint;
typedef unsigned short ushort;
typedef __bf16 bf16x8 __attribute__((ext_vector_type(8)));
typedef float f32x4 __attribute__((ext_vector_type(4)));

union ABu { bf16x8 v; ushort u[8]; };

// no clamp needed: exp2(+inf)->inf, rcp(inf)=0 -> +1;  exp2(-inf)->0 -> rcp(1)=1 -> -1
__device__ __forceinline__ float fast_tanh(float x) {
    float e = __expf(2.f * x);                 // mul + v_exp_f32
    return fmaf(-2.f, __builtin_amdgcn_rcpf(e + 1.f), 1.f);
}

// fp32 -> bf16 bits, RNE (slow path, used only in setup)
__device__ __forceinline__ ushort f2bf(float f) {
    uint u = __float_as_uint(f);
    uint r = (u + 0x7fffu + ((u >> 16) & 1u)) >> 16;
    return (ushort)r;
}

// RNE pack of two fp32 into one dword of two bf16 (lo=a, hi=b): 5 inst
__device__ __forceinline__ uint pack_bf16(float a, float b) {
    uint ua = __float_as_uint(a), ub = __float_as_uint(b);
    ua = ua + 0x7fffu + ((ua >> 16) & 1u);
    ub = ub + 0x7fffu + ((ub >> 16) & 1u);
    return __builtin_amdgcn_perm(ub, ua, 0x07060302u);  // [ua.hi16 | ub.hi16]
}

// LDS chunk layout for a 16(m) x 128(k) bf16 matrix: chunk (cc=k>>3, m) holds
// 8 consecutive k of row m at byte ((cc*16+m)*16 + (k&7)*2).  B-frag read for
// MFMA k-step s (quad q, lane m): one ds_read_b128 at ((s*4+q)*16+m)*16.
// Only rows m<RB are live; m>=RB feed discarded output columns (zero-inited).

__global__ void __launch_bounds__(NTHR, 1)
rinn_kernel(const float* __restrict__ obs, const float* __restrict__ x0,
            const float* __restrict__ A_T, const float* __restrict__ Bw_T,
            const float* __restrict__ By_T, const float* __restrict__ Cv_T,
            const float* __restrict__ Dvw_T, const float* __restrict__ Dvy_T,
            const float* __restrict__ Cu_T, const float* __restrict__ Duw_T,
            const float* __restrict__ Duy_T, const float* __restrict__ log_stds,
            float* __restrict__ out) {
    __shared__ __align__(16) char wbuf_raw[2][4096];  // w (16x128 bf16), dbuf
    __shared__ __align__(16) char xy_raw[2048];       // [x|y|0] (16x64 bf16)
    __shared__ float xs[RB][16];
    __shared__ float ls[OUT];

    const int tid  = threadIdx.x;
    const int wave = tid >> 6;
    const int lane = tid & 63;
    const int q    = lane >> 4;   // quad 0..3
    const int l15  = lane & 15;
    const int b0   = blockIdx.x * RB;
    const int c0   = wave * 16;   // this wave's 16-column tile of NL

    // ---- zero LDS (dead rows must not be NaN), load xs/ls ----
    ((uint4*)wbuf_raw)[tid] = uint4{0, 0, 0, 0};   // 512*16 = 8192 B
    if (tid < 512) ((uint*)xy_raw)[tid] = 0u;
    if (tid < RB * 16) { int m = tid >> 4, c = tid & 15; xs[m][c] = x0[(b0 + m) * S + c]; }
    if (tid < OUT) ls[tid] = log_stds[tid];

    // ---- preload MFMA A-operand fragments (iteration-invariant) ----
    // Z^T = Dvw^T (A) * w^T (B);  A[c][k]: c=c0+l15, k=32s+8q+j
    ABu Dfrag[4];
#pragma unroll
    for (int s = 0; s < 4; ++s)
#pragma unroll
        for (int j = 0; j < 8; ++j) {
            int k = 32 * s + 8 * q + j;
            Dfrag[s].u[j] = f2bf(Dvw_T[k * NL + c0 + l15]);
        }
    // cst^T = [Cv;Dvy;0]^T (A) * [x|y|0]^T (B), K=64
    ABu CB[2];
#pragma unroll
    for (int s = 0; s < 2; ++s)
#pragma unroll
        for (int j = 0; j < 8; ++j) {
            int k = 32 * s + 8 * q + j;
            float v = 0.f;
            if (k < 16) v = Cv_T[k * NL + c0 + l15];
            else if (k < 48) v = Dvy_T[(k - 16) * NL + c0 + l15];
            CB[s].u[j] = f2bf(v);
        }
    // epilogue: [u|xn]^T = W^T (A) * [x|y|0|w]^T (B), K=192, out rows 0..23
    ABu EP[6];
    if (wave < 2) {
        int oc = wave * 16 + l15;  // 0..7 = u, 8..23 = xnext, >=24 pad
#pragma unroll
        for (int s = 0; s < 6; ++s)
#pragma unroll
            for (int j = 0; j < 8; ++j) {
                int k = 32 * s + 8 * q + j;
                float v = 0.f;
                if (oc < 24) {
                    if (k < 16)      v = (oc < 8) ? Cu_T[k * OUT + oc]  : A_T[k * S + (oc - 8)];
                    else if (k < 48) { int ky = k - 16;
                                       v = (oc < 8) ? Duy_T[ky * OUT + oc] : By_T[ky * S + (oc - 8)]; }
                    else if (k >= 64) { int kw = k - 64;
                                       v = (oc < 8) ? Duw_T[kw * OUT + oc] : Bw_T[kw * S + (oc - 8)]; }
                }
                EP[s].u[j] = f2bf(v);
            }
    }

    const int rd_off = (q * 16 + l15) * 16;  // + s*1024
    const int waddr  = (((c0 >> 3) + (q >> 1)) * 16 + l15) * 16 + (q & 1) * 8;
    const bool wlive = (l15 < RB);

    __syncthreads();

    for (int t = 0; t < T; ++t) {
        // ---- stage [x|y] (rows < RB) ----
        if (tid < RB * 24) {
            int m = tid / 24, kp = tid % 24;
            int k = kp * 2;
            float v0, v1;
            if (k < 16) { v0 = xs[m][k]; v1 = xs[m][k + 1]; }
            else {
                const float* yp = obs + ((size_t)(b0 + m) * T + t) * IN + (k - 16);
                v0 = yp[0]; v1 = yp[1];
            }
            *(uint*)(xy_raw + ((k >> 3) * 16 + m) * 16 + ((k & 7) >> 1) * 4) =
                pack_bf16(v0, v1);
        }
        __syncthreads();

        // ---- cst (registers, fp32) ----
        f32x4 cst = {0.f, 0.f, 0.f, 0.f};
        {
            bf16x8 bx0 = *(const bf16x8*)(xy_raw + rd_off);
            bf16x8 bx1 = *(const bf16x8*)(xy_raw + rd_off + 1024);
            cst = __builtin_amdgcn_mfma_f32_16x16x32_bf16(CB[0].v, bx0, cst, 0, 0, 0);
            cst = __builtin_amdgcn_mfma_f32_16x16x32_bf16(CB[1].v, bx1, cst, 0, 0, 0);
        }

        // ---- iteration 1: w = tanh(cst) ----
        {
            uint2 pk;
            pk.x = pack_bf16(fast_tanh(cst.x), fast_tanh(cst.y));
            pk.y = pack_bf16(fast_tanh(cst.z), fast_tanh(cst.w));
            if (wlive) *(uint2*)(wbuf_raw[0] + waddr) = pk;
        }
        __syncthreads();

        // ---- iterations 2..30 ----
        int pb = 0;
        for (int it = 1; it < FP_ITERS; ++it) {
            const char* rb = wbuf_raw[pb];
            bf16x8 a0 = *(const bf16x8*)(rb + rd_off);
            bf16x8 a1 = *(const bf16x8*)(rb + rd_off + 1024);
            bf16x8 a2 = *(const bf16x8*)(rb + rd_off + 2048);
            bf16x8 a3 = *(const bf16x8*)(rb + rd_off + 3072);
            f32x4 acc0 = cst;                       // two independent chains
            f32x4 acc1 = {0.f, 0.f, 0.f, 0.f};
            acc0 = __builtin_amdgcn_mfma_f32_16x16x32_bf16(Dfrag[0].v, a0, acc0, 0, 0, 0);
            acc1 = __builtin_amdgcn_mfma_f32_16x16x32_bf16(Dfrag[1].v, a1, acc1, 0, 0, 0);
            acc0 = __builtin_amdgcn_mfma_f32_16x16x32_bf16(Dfrag[2].v, a2, acc0, 0, 0, 0);
            acc1 = __builtin_amdgcn_mfma_f32_16x16x32_bf16(Dfrag[3].v, a3, acc1, 0, 0, 0);
            float z0 = acc0.x + acc1.x, z1 = acc0.y + acc1.y;
            float z2 = acc0.z + acc1.z, z3 = acc0.w + acc1.w;
            uint2 pk;
            pk.x = pack_bf16(fast_tanh(z0), fast_tanh(z1));
            pk.y = pack_bf16(fast_tanh(z2), fast_tanh(z3));
            pb ^= 1;
            if (wlive) *(uint2*)(wbuf_raw[pb] + waddr) = pk;
            __syncthreads();
        }
        // final w in wbuf_raw[1]

        // ---- epilogue ----
        if (wave < 2) {
            f32x4 ea = {0.f, 0.f, 0.f, 0.f};
            bf16x8 bx0 = *(const bf16x8*)(xy_raw + rd_off);
            bf16x8 bx1 = *(const bf16x8*)(xy_raw + rd_off + 1024);
            ea = __builtin_amdgcn_mfma_f32_16x16x32_bf16(EP[0].v, bx0, ea, 0, 0, 0);
            ea = __builtin_amdgcn_mfma_f32_16x16x32_bf16(EP[1].v, bx1, ea, 0, 0, 0);
            const char* rb = wbuf_raw[1];
#pragma unroll
            for (int s = 0; s < 4; ++s) {
                bf16x8 aw = *(const bf16x8*)(rb + rd_off + s * 1024);
                ea = __builtin_amdgcn_mfma_f32_16x16x32_bf16(EP[2 + s].v, aw, ea, 0, 0, 0);
            }
            const int m = l15;
            float e[4] = {ea.x, ea.y, ea.z, ea.w};
            if (m < RB) {
                const size_t o = ((size_t)(b0 + m) * T + t) * (2 * OUT + 1);
                if (wave == 0) {
                    if (q < 2) {           // rows 0..7: u
#pragma unroll
                        for (int i = 0; i < 4; ++i) out[o + 4 * q + i] = e[i];
                    } else {               // rows 8..15: xnext cols 0..7
                        int cb = 4 * q - 8;
#pragma unroll
                        for (int i = 0; i < 4; ++i)
                            xs[m][cb + i] = fmaf(DT, e[i], xs[m][cb + i]);
                    }
                } else if (q < 2) {        // rows 16..23: xnext cols 8..15
                    int cb = 8 + 4 * q;
#pragma unroll
                    for (int i = 0; i < 4; ++i)
                        xs[m][cb + i] = fmaf(DT, e[i], xs[m][cb + i]);
                }
            }
        } else if (wave == 2 && l15 < RB) {  // log_stds
            const size_t o = ((size_t)(b0 + l15) * T + t) * (2 * OUT + 1);
            out[o + OUT + 2 * q]     = ls[2 * q];
            out[o + OUT + 2 * q + 1] = ls[2 * q + 1];
        }
        __syncthreads();
    }
}

// ---------------- value branch: 2 samples/thread (halve LDS reads) ----------
#define HALF_N (B * T / 2)   // 131072

__global__ void __launch_bounds__(256, 2)
value_kernel(const float* __restrict__ obs, const float* __restrict__ W0,
             const float* __restrict__ b0, const float* __restrict__ W1,
             const float* __restrict__ b1, const float* __restrict__ W2,
             const float* __restrict__ b2, float* __restrict__ out) {
    __shared__ float sW0[IN][64];
    __shared__ float sW1[64][64];
    __shared__ float sW2[64], sb0[64], sb1[64];
    __shared__ float sb2;
    const int tid = threadIdx.x;
    for (int i = tid; i < IN * 64; i += 256) ((float*)sW0)[i] = W0[i];
    for (int i = tid; i < 64 * 64; i += 256) ((float*)sW1)[i] = W1[i];
    if (tid < 64) { sW2[tid] = W2[tid]; sb0[tid] = b0[tid]; sb1[tid] = b1[tid]; }
    if (tid == 0) sb2 = b2[0];
    __syncthreads();

    const size_t s0 = (size_t)blockIdx.x * 256 + tid;   // [0, HALF_N)
    const size_t s1 = s0 + HALF_N;
    float o0[IN], o1[IN];
#pragma unroll
    for (int qq = 0; qq < IN / 4; ++qq) {
        float4 v = ((const float4*)(obs + s0 * IN))[qq];
        o0[4 * qq] = v.x; o0[4 * qq + 1] = v.y; o0[4 * qq + 2] = v.z; o0[4 * qq + 3] = v.w;
        float4 w = ((const float4*)(obs + s1 * IN))[qq];
        o1[4 * qq] = w.x; o1[4 * qq + 1] = w.y; o1[4 * qq + 2] = w.z; o1[4 * qq + 3] = w.w;
    }
    float h0[64], h1[64];
#pragma unroll
    for (int jg = 0; jg < 16; ++jg) {
        float4 bias = *(const float4*)&sb0[4 * jg];
        float4 a = bias, c = bias;
#pragma unroll
        for (int i = 0; i < IN; ++i) {
            float4 wrow = *(const float4*)&sW0[i][4 * jg];
            a.x = fmaf(o0[i], wrow.x, a.x); a.y = fmaf(o0[i], wrow.y, a.y);
            a.z = fmaf(o0[i], wrow.z, a.z); a.w = fmaf(o0[i], wrow.w, a.w);
            c.x = fmaf(o1[i], wrow.x, c.x); c.y = fmaf(o1[i], wrow.y, c.y);
            c.z = fmaf(o1[i], wrow.z, c.z); c.w = fmaf(o1[i], wrow.w, c.w);
        }
        h0[4 * jg]     = fast_tanh(a.x); h0[4 * jg + 1] = fast_tanh(a.y);
        h0[4 * jg + 2] = fast_tanh(a.z); h0[4 * jg + 3] = fast_tanh(a.w);
        h1[4 * jg]     = fast_tanh(c.x); h1[4 * jg + 1] = fast_tanh(c.y);
        h1[4 * jg + 2] = fast_tanh(c.z); h1[4 * jg + 3] = fast_tanh(c.w);
    }
    float v0 = sb2, v1 = sb2;
#pragma unroll
    for (int jg = 0; jg < 16; ++jg) {
        float4 bias = *(const float4*)&sb1[4 * jg];
        float4 a = bias, c = bias;
#pragma unroll
        for (int i = 0; i < 64; ++i) {
            float4 wrow = *(const float4*)&sW1[i][4 * jg];
            a.x = fmaf(h0[i], wrow.x, a.x); a.y = fmaf(h0[i], wrow.y, a.y);
            a.z = fmaf(h0[i], wrow.z, a.z); a.w = fmaf(h0[i], wrow.w, a.w);
            c.x = fmaf(h1[i], wrow.x, c.x); c.y = fmaf(h1[i], wrow.y, c.y);
            c.z = fmaf(h1[i], wrow.z, c.z); c.w = fmaf(h1[i], wrow.w, c.w);
        }
        float4 w2 = *(const float4*)&sW2[4 * jg];
        v0 = fmaf(fast_tanh(a.x), w2.x, v0); v0 = fmaf(fast_tanh(a.y), w2.y, v0);
        v0 = fmaf(fast_tanh(a.z), w2.z, v0); v0 = fmaf(fast_tanh(a.w), w2.w, v0);
        v1 = fmaf(fast_tanh(c.x), w2.x, v1); v1 = fmaf(fast_tanh(c.y), w2.y, v1);
        v1 = fmaf(fast_tanh(c.z), w2.z, v1); v1 = fmaf(fast_tanh(c.w), w2.w, v1);
    }
    out[s0 * (2 * OUT + 1) + 2 * OUT] = v0;
    out[s1 * (2 * OUT + 1) + 2 * OUT] = v1;
}

extern "C" void kernel_launch(void* const* d_in, const int* in_sizes, int n_in,
                              void* d_out, int out_size, void* d_ws, size_t ws_size,
                              hipStream_t stream) {
    const float* obs      = (const float*)d_in[0];
    const float* x0       = (const float*)d_in[1];
    const float* A_T      = (const float*)d_in[2];
    const float* Bw_T     = (const float*)d_in[3];
    const float* By_T     = (const float*)d_in[4];
    const float* Cv_T     = (const float*)d_in[5];
    const float* Dvw_T    = (const float*)d_in[6];
    const float* Dvy_T    = (const float*)d_in[7];
    const float* Cu_T     = (const float*)d_in[8];
    const float* Duw_T    = (const float*)d_in[9];
    const float* Duy_T    = (const float*)d_in[10];
    const float* log_stds = (const float*)d_in[11];
    const float* W0       = (const float*)d_in[12];
    const float* b0       = (const float*)d_in[13];
    const float* W1       = (const float*)d_in[14];
    const float* b1       = (const float*)d_in[15];
    const float* W2       = (const float*)d_in[16];
    const float* b2       = (const float*)d_in[17];
    float* out = (float*)d_out;

    rinn_kernel<<<NBLK, NTHR, 0, stream>>>(
        obs, x0, A_T, Bw_T, By_T, Cv_T, Dvw_T, Dvy_T, Cu_T, Duw_T, Duy_T,
        log_stds, out);
    value_kernel<<<HALF_N / 256, 256, 0, stream>>>(obs, W0, b0, W1, b1, W2, b2,
                                                   out);
}